// Round 1
// baseline (102.950 us; speedup 1.0000x reference)
//
#include <hip/hip_runtime.h>
#include <math.h>

#define KS 3
#define NB 6      // GRID_N + K = 6 basis functions
#define NKNOT 10  // GRID_N + 2K + 1

struct Params {
    float c0[3][NB];
    float sb0[3], sp0[3];
    float b0;
    float c1[NB];
    float sb1, sp1;
    float ki0, ki1;
};

#define FDIV(a, b) __fdividef((a), (b))

// Cubic B-spline basis (6 funcs) + derivative on the reference's fixed grid.
// Exactly mirrors the reference recursion (incl. indicator boundary semantics)
// and its autodiff (product rule; indicators have zero derivative).
__device__ __forceinline__ void bspline6(float x, float B[NB], float dB[NB]) {
    const float h = 2.0f / 3.0f;
    float t[NKNOT];
#pragma unroll
    for (int j = 0; j < NKNOT; ++j) t[j] = -1.0f + h * (float)(j - KS);
    float Bp[9], Dp[9];
#pragma unroll
    for (int j = 0; j < 9; ++j) {
        Bp[j] = (x >= t[j] && x < t[j + 1]) ? 1.0f : 0.0f;
        Dp[j] = 0.0f;
    }
#pragma unroll
    for (int p = 1; p <= KS; ++p) {
        const float inv = 1.0f / (h * (float)p);  // uniform knots: both denoms = p*h
#pragma unroll
        for (int j = 0; j + p < 9; ++j) {
            float u  = (x - t[j]) * inv;
            float v  = (t[j + p + 1] - x) * inv;
            float nb = u * Bp[j] + v * Bp[j + 1];
            float nd = inv * (Bp[j] - Bp[j + 1]) + u * Dp[j] + v * Dp[j + 1];
            Bp[j] = nb;
            Dp[j] = nd;
        }
    }
#pragma unroll
    for (int j = 0; j < NB; ++j) { B[j] = Bp[j]; dB[j] = Dp[j]; }
}

__device__ __forceinline__ void silu_fd(float x, float& s, float& ds) {
    float sig = FDIV(1.0f, 1.0f + __expf(-x));
    s  = x * sig;
    ds = sig * (1.0f + x * (1.0f - sig));
}

// Analytic gradient of W(s1,s2,s3) (one sample).
__device__ void grad_sample(float s1, float s2, float s3, const Params& P, float g[3]) {
    float a   = 2.0f * s1 + 1.0f;
    float d   = 2.0f * s2 + 1.0f;
    float b   = s3;
    float det = a * d - b * b;
    float invDet = FDIV(1.0f, det);
    float logJ = 0.5f * __logf(det);
    float m    = 0.5f * (a + d);
    float amd  = a - d;
    float h2   = 0.25f * amd * amd + b * b;
    bool  pos  = h2 > 0.0f;
    float r    = pos ? __builtin_sqrtf(h2) : 0.0f;
    float ir2  = pos ? FDIV(0.5f, r) : 0.0f;  // dr/dX = h2_X * ir2 ; 0 at h2<=0 (JAX where)
    float dr[3];
    dr[0] =  0.5f * amd * ir2;
    dr[1] = -0.5f * amd * ir2;
    dr[2] =  2.0f * b   * ir2;
    const float dm[3]   = {0.5f, 0.5f, 0.0f};
    const float dDet[3] = {d, a, -2.0f * b};
    float e1 = __builtin_sqrtf(m - r), e2 = __builtin_sqrtf(m + r);
    float aux  = __powf(det, -1.0f / 6.0f);
    float reg1 = e1 * aux, reg2 = e2 * aux;
    float x0 = __powf(reg1, P.ki0);
    float x1 = __powf(reg2, P.ki0);
    float x2 = logJ * P.ki1;

    // ---- layer 1: forward h and local grads dh/dx_i ----
    float xs[3] = {x0, x1, x2};
    float hacc  = P.b0;
    float gx[3];
#pragma unroll
    for (int i = 0; i < 3; ++i) {
        float B[NB], dB[NB];
        bspline6(xs[i], B, dB);
        float sp = 0.0f, dsp = 0.0f;
#pragma unroll
        for (int k = 0; k < NB; ++k) {
            sp  = fmaf(P.c0[i][k], B[k],  sp);
            dsp = fmaf(P.c0[i][k], dB[k], dsp);
        }
        float si, dsi; silu_fd(xs[i], si, dsi);
        hacc += P.sb0[i] * si + P.sp0[i] * sp;
        gx[i] = P.sb0[i] * dsi + P.sp0[i] * dsp;
    }
    // ---- layer 2: dW/dh ----
    float B2[NB], dB2[NB];
    bspline6(hacc, B2, dB2);
    float sp2 = 0.0f, dsp2 = 0.0f;
#pragma unroll
    for (int k = 0; k < NB; ++k) {
        sp2  = fmaf(P.c1[k], B2[k],  sp2);
        dsp2 = fmaf(P.c1[k], dB2[k], dsp2);
    }
    float si2, dsi2; silu_fd(hacc, si2, dsi2);
    float dWdh = P.sb1 * dsi2 + P.sp1 * dsp2;

    float w0 = dWdh * gx[0];
    float w1 = dWdh * gx[1];
    float w2 = dWdh * gx[2];

    float pw1  = P.ki0 * FDIV(x0, reg1);  // ki0 * reg1^(ki0-1)
    float pw2  = P.ki0 * FDIV(x1, reg2);
    float i2e1 = FDIV(0.5f, e1), i2e2 = FDIV(0.5f, e2);
    float auxs = -aux * invDet * (1.0f / 6.0f);
    float gadb[3];
#pragma unroll
    for (int X = 0; X < 3; ++X) {
        float de1   = (dm[X] - dr[X]) * i2e1;
        float de2   = (dm[X] + dr[X]) * i2e2;
        float daux  = auxs * dDet[X];
        float dreg1 = aux * de1 + e1 * daux;
        float dreg2 = aux * de2 + e2 * daux;
        float dx0   = pw1 * dreg1;
        float dx1   = pw2 * dreg2;
        float dx2   = P.ki1 * 0.5f * invDet * dDet[X];
        gadb[X] = w0 * dx0 + w1 * dx1 + w2 * dx2;
    }
    g[0] = 2.0f * gadb[0];  // da/ds1 = 2
    g[1] = 2.0f * gadb[1];  // dd/ds2 = 2
    g[2] = gadb[2];         // db/ds3 = 1
}

__global__ __launch_bounds__(256) void kan_grad(
        const float* __restrict__ strain, float* __restrict__ out, int n,
        const float* __restrict__ c0, const float* __restrict__ sb0,
        const float* __restrict__ sp0, const float* __restrict__ b0,
        const float* __restrict__ c1, const float* __restrict__ sb1,
        const float* __restrict__ sp1, const float* __restrict__ ki0,
        const float* __restrict__ ki1) {
    Params P;
#pragma unroll
    for (int i = 0; i < 3; ++i) {
#pragma unroll
        for (int k = 0; k < NB; ++k) P.c0[i][k] = c0[i * NB + k];
        P.sb0[i] = sb0[i];
        P.sp0[i] = sp0[i];
    }
    P.b0 = b0[0];
#pragma unroll
    for (int k = 0; k < NB; ++k) P.c1[k] = c1[k];
    P.sb1 = sb1[0]; P.sp1 = sp1[0];
    P.ki0 = ki0[0]; P.ki1 = ki1[0];

    // grad at zero strain: once per block (lane 0) into LDS.
    __shared__ float g0s[3];
    if (threadIdx.x == 0) {
        float g0[3];
        grad_sample(0.0f, 0.0f, 0.0f, P, g0);
        g0s[0] = g0[0]; g0s[1] = g0[1]; g0s[2] = g0[2];
    }
    __syncthreads();
    const float g00 = g0s[0], g01 = g0s[1], g02 = g0s[2];

    const int ngroups = (n + 3) >> 2;  // 4 samples (= 3 float4) per thread-task
    for (int gi = blockIdx.x * blockDim.x + threadIdx.x; gi < ngroups;
         gi += gridDim.x * blockDim.x) {
        int i0 = gi * 4;
        if (i0 + 4 <= n) {
            const float4* sp4 = reinterpret_cast<const float4*>(strain + (size_t)i0 * 3);
            float4 v0 = sp4[0], v1 = sp4[1], v2 = sp4[2];
            float in[12] = {v0.x, v0.y, v0.z, v0.w,
                            v1.x, v1.y, v1.z, v1.w,
                            v2.x, v2.y, v2.z, v2.w};
            float o[12];
#pragma unroll
            for (int k = 0; k < 4; ++k) {
                float g[3];
                grad_sample(in[3 * k], in[3 * k + 1], in[3 * k + 2], P, g);
                o[3 * k]     = g[0] - g00;
                o[3 * k + 1] = g[1] - g01;
                o[3 * k + 2] = g[2] - g02;
            }
            float4* op4 = reinterpret_cast<float4*>(out + (size_t)i0 * 3);
            op4[0] = make_float4(o[0], o[1], o[2],  o[3]);
            op4[1] = make_float4(o[4], o[5], o[6],  o[7]);
            op4[2] = make_float4(o[8], o[9], o[10], o[11]);
        } else {
            for (int i = i0; i < n; ++i) {
                float g[3];
                grad_sample(strain[3 * i], strain[3 * i + 1], strain[3 * i + 2], P, g);
                out[3 * i]     = g[0] - g00;
                out[3 * i + 1] = g[1] - g01;
                out[3 * i + 2] = g[2] - g02;
            }
        }
    }
}

extern "C" void kernel_launch(void* const* d_in, const int* in_sizes, int n_in,
                              void* d_out, int out_size, void* d_ws, size_t ws_size,
                              hipStream_t stream) {
    const float* strain = (const float*)d_in[0];
    const float* c0  = (const float*)d_in[1];
    const float* sb0 = (const float*)d_in[2];
    const float* sp0 = (const float*)d_in[3];
    const float* b0  = (const float*)d_in[4];
    const float* c1  = (const float*)d_in[5];
    const float* sb1 = (const float*)d_in[6];
    const float* sp1 = (const float*)d_in[7];
    // d_in[8] = b1: no effect on gradient
    const float* ki0 = (const float*)d_in[9];
    const float* ki1 = (const float*)d_in[10];

    int n = in_sizes[0] / 3;                 // number of samples
    int ngroups = (n + 3) / 4;
    int block = 256;
    int grid = (ngroups + block - 1) / block;
    if (grid > 8192) grid = 8192;

    kan_grad<<<grid, block, 0, stream>>>(strain, (float*)d_out, n,
                                         c0, sb0, sp0, b0, c1, sb1, sp1, ki0, ki1);
}

// Round 3
// 57.370 us; speedup vs baseline: 1.7945x; 1.7945x over previous
//
#include <hip/hip_runtime.h>
#include <math.h>

#define NB 6   // GRID_N + K basis functions

struct Params {
    float sb0[3], sp0[3];
    float b0;
    float sb1, sp1;
    float ki0, ki1;
};

#define FDIV(a, b) __fdividef((a), (b))

// Closed-form uniform cubic B-spline: dot of the 4 nonzero basis (and their
// derivatives) with zero-padded coefficients cpad[12] (cpad[3..8]=c[0..5]).
// For x in knot cell [t_i, t_{i+1}), f = u - i:
//   coeff c[i-3] (cpad[i  ]): (1-f)^3/6
//   coeff c[i-2] (cpad[i+1]): (3f^3-6f^2+4)/6
//   coeff c[i-1] (cpad[i+2]): (-3f^3+3f^2+3f+1)/6
//   coeff c[i  ] (cpad[i+3]): f^3/6
// Outside [t0,t9) all basis vanish (mask); boundary partial sums fall out of
// the zero pads. Matches the reference Cox-de Boor recursion exactly.
__device__ __forceinline__ void spline_dot(float x, const float* __restrict__ cpad,
                                           float& sp, float& dsp) {
    float u  = fmaf(x, 1.5f, 4.5f);      // (x + 3) / h, h = 2/3
    float fi = floorf(u);
    float f  = u - fi;
    int   i  = (int)fi;
    float msk = (u >= 0.0f && u < 9.0f) ? 1.0f : 0.0f;
    i = i < 0 ? 0 : (i > 8 ? 8 : i);

    float f2 = f * f, f3 = f2 * f;
    float omf = 1.0f - f, omf2 = omf * omf, omf3 = omf2 * omf;
    const float c16 = 1.0f / 6.0f;
    float w0 = omf3 * c16;                       // -> cpad[i]
    float w1 = 0.5f * f3 - f2 + 4.0f * c16;      // -> cpad[i+1]
    float w3 = f3 * c16;                         // -> cpad[i+3]
    float w2 = 1.0f - w0 - w1 - w3;              // -> cpad[i+2] (partition of unity)
    // d/dx = (d/df) * 1.5
    float d0 = -0.5f * omf2 * 1.5f;
    float d1 = (1.5f * f2 - 2.0f * f) * 1.5f;
    float d3 =  0.5f * f2   * 1.5f;
    float d2 = -(d0 + d1 + d3);                  // derivatives sum to 0

    float c0 = cpad[i], c1 = cpad[i + 1], c2 = cpad[i + 2], c3 = cpad[i + 3];
    sp  = msk * (c0 * w0 + c1 * w1 + c2 * w2 + c3 * w3);
    dsp = msk * (c0 * d0 + c1 * d1 + c2 * d2 + c3 * d3);
}

__device__ __forceinline__ void silu_fd(float x, float& s, float& ds) {
    float sig = FDIV(1.0f, 1.0f + __expf(-x));
    s  = x * sig;
    ds = sig * (1.0f + x * (1.0f - sig));
}

// Analytic gradient of W(s1,s2,s3) (one sample). Coefs come from LDS pads.
__device__ void grad_sample(float s1, float s2, float s3, const Params& P,
                            const float (*__restrict__ c0pad)[12],
                            const float* __restrict__ c1pad, float g[3]) {
    float a   = 2.0f * s1 + 1.0f;
    float d   = 2.0f * s2 + 1.0f;
    float b   = s3;
    float det = a * d - b * b;
    float invDet = FDIV(1.0f, det);
    float logJ = 0.5f * __logf(det);
    float m    = 0.5f * (a + d);
    float amd  = a - d;
    float h2   = 0.25f * amd * amd + b * b;
    bool  pos  = h2 > 0.0f;
    float r    = pos ? __builtin_sqrtf(h2) : 0.0f;
    float ir2  = pos ? FDIV(0.5f, r) : 0.0f;  // JAX `where`: dr = 0 at h2<=0
    float dr0 =  0.5f * amd * ir2;
    float dr1 = -0.5f * amd * ir2;
    float dr2 =  2.0f * b   * ir2;
    float e1 = __builtin_sqrtf(m - r), e2 = __builtin_sqrtf(m + r);
    float aux  = __powf(det, -1.0f / 6.0f);
    float reg1 = e1 * aux, reg2 = e2 * aux;
    float x0 = __powf(reg1, P.ki0);
    float x1 = __powf(reg2, P.ki0);
    float x2 = logJ * P.ki1;

    // ---- layer 1: forward h and local grads dh/dx_i ----
    float xs[3] = {x0, x1, x2};
    float hacc  = P.b0;
    float gx[3];
#pragma unroll
    for (int i = 0; i < 3; ++i) {
        float sp, dsp;
        spline_dot(xs[i], c0pad[i], sp, dsp);
        float si, dsi; silu_fd(xs[i], si, dsi);
        hacc += P.sb0[i] * si + P.sp0[i] * sp;
        gx[i] = P.sb0[i] * dsi + P.sp0[i] * dsp;
    }
    // ---- layer 2: dW/dh ----
    float sp2, dsp2;
    spline_dot(hacc, c1pad, sp2, dsp2);
    float si2, dsi2; silu_fd(hacc, si2, dsi2);
    float dWdh = P.sb1 * dsi2 + P.sp1 * dsp2;

    float w0 = dWdh * gx[0];
    float w1 = dWdh * gx[1];
    float w2 = dWdh * gx[2];

    float pw1  = P.ki0 * FDIV(x0, reg1);  // ki0 * reg1^(ki0-1)
    float pw2  = P.ki0 * FDIV(x1, reg2);
    float i2e1 = FDIV(0.5f, e1), i2e2 = FDIV(0.5f, e2);
    float auxs = -aux * invDet * (1.0f / 6.0f);

    const float dm[3]   = {0.5f, 0.5f, 0.0f};
    const float dDet[3] = {d, a, -2.0f * b};
    const float drv[3]  = {dr0, dr1, dr2};
    float gadb[3];
#pragma unroll
    for (int X = 0; X < 3; ++X) {
        float de1   = (dm[X] - drv[X]) * i2e1;
        float de2   = (dm[X] + drv[X]) * i2e2;
        float daux  = auxs * dDet[X];
        float dreg1 = aux * de1 + e1 * daux;
        float dreg2 = aux * de2 + e2 * daux;
        float dx0   = pw1 * dreg1;
        float dx1   = pw2 * dreg2;
        float dx2   = P.ki1 * 0.5f * invDet * dDet[X];
        gadb[X] = w0 * dx0 + w1 * dx1 + w2 * dx2;
    }
    g[0] = 2.0f * gadb[0];  // da/ds1 = 2
    g[1] = 2.0f * gadb[1];  // dd/ds2 = 2
    g[2] = gadb[2];         // db/ds3 = 1
}

__global__ __launch_bounds__(256) void kan_grad(
        const float* __restrict__ strain, float* __restrict__ out, int n,
        const float* __restrict__ c0, const float* __restrict__ sb0,
        const float* __restrict__ sp0, const float* __restrict__ b0,
        const float* __restrict__ c1, const float* __restrict__ sb1,
        const float* __restrict__ sp1, const float* __restrict__ ki0,
        const float* __restrict__ ki1) {
    __shared__ float c0pad[3][12];
    __shared__ float c1pad[12];
    __shared__ float g0s[3];

    const int t = threadIdx.x;
    if (t < 48) {
        if (t < 36) {
            int i = t / 12, k = t % 12;
            c0pad[i][k] = (k >= 3 && k < 9) ? c0[i * NB + (k - 3)] : 0.0f;
        } else {
            int k = t - 36;
            c1pad[k] = (k >= 3 && k < 9) ? c1[k - 3] : 0.0f;
        }
    }

    Params P;
#pragma unroll
    for (int i = 0; i < 3; ++i) { P.sb0[i] = sb0[i]; P.sp0[i] = sp0[i]; }
    P.b0 = b0[0];
    P.sb1 = sb1[0]; P.sp1 = sp1[0];
    P.ki0 = ki0[0]; P.ki1 = ki1[0];

    __syncthreads();
    if (t == 0) {
        float g0[3];
        grad_sample(0.0f, 0.0f, 0.0f, P, c0pad, c1pad, g0);
        g0s[0] = g0[0]; g0s[1] = g0[1]; g0s[2] = g0[2];
    }
    __syncthreads();
    const float g00 = g0s[0], g01 = g0s[1], g02 = g0s[2];

    const int ngroups = (n + 3) >> 2;  // 4 samples (= 3 float4) per thread-task
    for (int gi = blockIdx.x * blockDim.x + threadIdx.x; gi < ngroups;
         gi += gridDim.x * blockDim.x) {
        int i0 = gi * 4;
        if (i0 + 4 <= n) {
            const float4* sp4 = reinterpret_cast<const float4*>(strain + (size_t)i0 * 3);
            float4 v0 = sp4[0], v1 = sp4[1], v2 = sp4[2];
            float in[12] = {v0.x, v0.y, v0.z, v0.w,
                            v1.x, v1.y, v1.z, v1.w,
                            v2.x, v2.y, v2.z, v2.w};
            float o[12];
#pragma unroll
            for (int k = 0; k < 4; ++k) {
                float g[3];
                grad_sample(in[3 * k], in[3 * k + 1], in[3 * k + 2], P, c0pad, c1pad, g);
                o[3 * k]     = g[0] - g00;
                o[3 * k + 1] = g[1] - g01;
                o[3 * k + 2] = g[2] - g02;
            }
            float4* op4 = reinterpret_cast<float4*>(out + (size_t)i0 * 3);
            op4[0] = make_float4(o[0], o[1], o[2],  o[3]);
            op4[1] = make_float4(o[4], o[5], o[6],  o[7]);
            op4[2] = make_float4(o[8], o[9], o[10], o[11]);
        } else {
            for (int i = i0; i < n; ++i) {
                float g[3];
                grad_sample(strain[3 * i], strain[3 * i + 1], strain[3 * i + 2], P,
                            c0pad, c1pad, g);
                out[3 * i]     = g[0] - g00;
                out[3 * i + 1] = g[1] - g01;
                out[3 * i + 2] = g[2] - g02;
            }
        }
    }
}

extern "C" void kernel_launch(void* const* d_in, const int* in_sizes, int n_in,
                              void* d_out, int out_size, void* d_ws, size_t ws_size,
                              hipStream_t stream) {
    const float* strain = (const float*)d_in[0];
    const float* c0  = (const float*)d_in[1];
    const float* sb0 = (const float*)d_in[2];
    const float* sp0 = (const float*)d_in[3];
    const float* b0  = (const float*)d_in[4];
    const float* c1  = (const float*)d_in[5];
    const float* sb1 = (const float*)d_in[6];
    const float* sp1 = (const float*)d_in[7];
    // d_in[8] = b1: no effect on gradient
    const float* ki0 = (const float*)d_in[9];
    const float* ki1 = (const float*)d_in[10];

    int n = in_sizes[0] / 3;                 // number of samples
    int ngroups = (n + 3) / 4;
    int block = 256;
    int grid = (ngroups + block - 1) / block;
    if (grid > 8192) grid = 8192;

    kan_grad<<<grid, block, 0, stream>>>(strain, (float*)d_out, n,
                                         c0, sb0, sp0, b0, c1, sb1, sp1, ki0, ki1);
}

// Round 4
// 26.294 us; speedup vs baseline: 3.9154x; 2.1819x over previous
//
#include <hip/hip_runtime.h>
#include <math.h>

#define NB 6   // GRID_N + K basis functions

struct Params {
    float sb0[3], sp0[3];
    float b0;
    float sb1, sp1;
    float ki0, ki1;
};

__device__ __forceinline__ float fexp2(float x) { return __builtin_amdgcn_exp2f(x); }
__device__ __forceinline__ float flog2(float x) { return __builtin_amdgcn_logf(x); }
__device__ __forceinline__ float frcp(float x)  { return __builtin_amdgcn_rcpf(x); }
__device__ __forceinline__ float frsq(float x)  { return __builtin_amdgcn_rsqf(x); }

// Closed-form uniform cubic B-spline (validated round 3): dot of the 4
// nonzero basis (and derivatives) with zero-padded coefficients cpad[12].
__device__ __forceinline__ void spline_dot(float x, const float* __restrict__ cpad,
                                           float& sp, float& dsp) {
    float u  = fmaf(x, 1.5f, 4.5f);      // (x + 3) / h, h = 2/3
    float fi = floorf(u);
    float f  = u - fi;
    int   i  = (int)fi;
    float msk = (u >= 0.0f && u < 9.0f) ? 1.0f : 0.0f;
    i = i < 0 ? 0 : (i > 8 ? 8 : i);

    float f2 = f * f, f3 = f2 * f;
    float omf = 1.0f - f, omf2 = omf * omf, omf3 = omf2 * omf;
    const float c16 = 1.0f / 6.0f;
    float w0 = omf3 * c16;                       // -> cpad[i]
    float w1 = 0.5f * f3 - f2 + 4.0f * c16;      // -> cpad[i+1]
    float w3 = f3 * c16;                         // -> cpad[i+3]
    float w2 = 1.0f - w0 - w1 - w3;              // -> cpad[i+2]
    float d0 = -0.5f * omf2 * 1.5f;
    float d1 = (1.5f * f2 - 2.0f * f) * 1.5f;
    float d3 =  0.5f * f2   * 1.5f;
    float d2 = -(d0 + d1 + d3);

    float c0 = cpad[i], c1 = cpad[i + 1], c2 = cpad[i + 2], c3 = cpad[i + 3];
    sp  = msk * (c0 * w0 + c1 * w1 + c2 * w2 + c3 * w3);
    dsp = msk * (c0 * d0 + c1 * d1 + c2 * d2 + c3 * d3);
}

__device__ __forceinline__ void silu_fd(float x, float& s, float& ds) {
    float e   = fexp2(-1.44269504f * x);
    float sig = frcp(1.0f + e);
    s  = x * sig;
    ds = sig * (1.0f + x * (1.0f - sig));
}

// Analytic gradient of W(s1,s2,s3), log2-space formulation:
//   t1 = m - r, t2 = m + r   (squared eigenvalues; det = t1*t2)
//   x0 = t1^(k/2) det^(-k/6) = exp2(k(Lt1/3 - Lt2/6)),  x1 symmetric
//   x2 = ki1 * 0.5 * ln(det)
//   dx0/dX = x0*k*(0.5*dt1/t1 - dDet/(6 det)),  dt1 = dm - dr, dt2 = dm + dr
//   => gadb[X] = (A+B)*dm[X] + (B-A)*dr[X] + C*dDet[X]
// JAX where-guard: dr = 0 when h2 <= 0 (irr selected to 0).
__device__ void grad_sample(float s1, float s2, float s3, const Params& P,
                            const float (*__restrict__ c0pad)[12],
                            const float* __restrict__ c1pad, float g[3]) {
    float a   = fmaf(2.0f, s1, 1.0f);
    float d   = fmaf(2.0f, s2, 1.0f);
    float b   = s3;
    float m   = 0.5f * (a + d);
    float amd = a - d;
    float h2  = fmaf(0.25f * amd, amd, b * b);
    bool  pos = h2 > 0.0f;
    float irr = pos ? frsq(h2) : 0.0f;   // 1/r  (0 at h2<=0, per JAX where)
    float r   = h2 * irr;                 // sqrt(h2), exactly 0 at h2<=0
    float t1  = m - r, t2 = m + r;
    float invt1 = frcp(t1), invt2 = frcp(t2);
    float invDet = invt1 * invt2;
    float Lt1 = flog2(t1), Lt2 = flog2(t2);
    float k   = P.ki0;
    float x0  = fexp2(k * (Lt1 * (1.0f / 3.0f) - Lt2 * (1.0f / 6.0f)));
    float x1  = fexp2(k * (Lt2 * (1.0f / 3.0f) - Lt1 * (1.0f / 6.0f)));
    float x2  = P.ki1 * 0.34657359f * (Lt1 + Lt2);   // ki1 * 0.5*ln2*log2(det)

    // ---- layer 1: forward h and local grads dh/dx_i ----
    float xs[3] = {x0, x1, x2};
    float hacc  = P.b0;
    float gx[3];
#pragma unroll
    for (int i = 0; i < 3; ++i) {
        float sp, dsp;
        spline_dot(xs[i], c0pad[i], sp, dsp);
        float si, dsi; silu_fd(xs[i], si, dsi);
        hacc += P.sb0[i] * si + P.sp0[i] * sp;
        gx[i] = P.sb0[i] * dsi + P.sp0[i] * dsp;
    }
    // ---- layer 2: dW/dh ----
    float sp2, dsp2;
    spline_dot(hacc, c1pad, sp2, dsp2);
    float si2, dsi2; silu_fd(hacc, si2, dsi2);
    float dWdh = P.sb1 * dsi2 + P.sp1 * dsp2;

    // ---- collapse to strain gradient ----
    float P0 = dWdh * gx[0] * x0 * k;
    float P1 = dWdh * gx[1] * x1 * k;
    float w2c = dWdh * gx[2];
    float A = 0.5f * P0 * invt1;
    float B = 0.5f * P1 * invt2;
    float C = invDet * (0.5f * P.ki1 * w2c - (P0 + P1) * (1.0f / 6.0f));
    float dr0 = 0.25f * amd * irr;       // dr/da = -dr/dd
    float dr2 = b * irr;                 // dr/db
    float ApB = A + B, BmA = B - A;
    float h05 = 0.5f * ApB;
    float gA = h05 + BmA * dr0 + C * d;
    float gD = h05 - BmA * dr0 + C * a;
    float gB = BmA * dr2 - 2.0f * b * C;
    g[0] = 2.0f * gA;   // da/ds1 = 2
    g[1] = 2.0f * gD;   // dd/ds2 = 2
    g[2] = gB;          // db/ds3 = 1
}

__global__ __launch_bounds__(256) void kan_grad(
        const float* __restrict__ strain, float* __restrict__ out, int n,
        const float* __restrict__ c0, const float* __restrict__ sb0,
        const float* __restrict__ sp0, const float* __restrict__ b0,
        const float* __restrict__ c1, const float* __restrict__ sb1,
        const float* __restrict__ sp1, const float* __restrict__ ki0,
        const float* __restrict__ ki1) {
    __shared__ float c0pad[3][12];
    __shared__ float c1pad[12];
    __shared__ float g0s[3];

    const int t = threadIdx.x;
    if (t < 48) {
        if (t < 36) {
            int i = t / 12, k = t % 12;
            c0pad[i][k] = (k >= 3 && k < 9) ? c0[i * NB + (k - 3)] : 0.0f;
        } else {
            int k = t - 36;
            c1pad[k] = (k >= 3 && k < 9) ? c1[k - 3] : 0.0f;
        }
    }

    Params P;
#pragma unroll
    for (int i = 0; i < 3; ++i) { P.sb0[i] = sb0[i]; P.sp0[i] = sp0[i]; }
    P.b0 = b0[0];
    P.sb1 = sb1[0]; P.sp1 = sp1[0];
    P.ki0 = ki0[0]; P.ki1 = ki1[0];

    __syncthreads();
    if (t == 0) {
        float g0[3];
        grad_sample(0.0f, 0.0f, 0.0f, P, c0pad, c1pad, g0);
        g0s[0] = g0[0]; g0s[1] = g0[1]; g0s[2] = g0[2];
    }
    __syncthreads();
    const float g00 = g0s[0], g01 = g0s[1], g02 = g0s[2];

    const int ngroups = (n + 3) >> 2;  // 4 samples (= 3 float4) per thread-task
    for (int gi = blockIdx.x * blockDim.x + threadIdx.x; gi < ngroups;
         gi += gridDim.x * blockDim.x) {
        int i0 = gi * 4;
        if (i0 + 4 <= n) {
            const float4* sp4 = reinterpret_cast<const float4*>(strain + (size_t)i0 * 3);
            float4 v0 = sp4[0], v1 = sp4[1], v2 = sp4[2];
            float in[12] = {v0.x, v0.y, v0.z, v0.w,
                            v1.x, v1.y, v1.z, v1.w,
                            v2.x, v2.y, v2.z, v2.w};
            float o[12];
#pragma unroll
            for (int k = 0; k < 4; ++k) {
                float g[3];
                grad_sample(in[3 * k], in[3 * k + 1], in[3 * k + 2], P, c0pad, c1pad, g);
                o[3 * k]     = g[0] - g00;
                o[3 * k + 1] = g[1] - g01;
                o[3 * k + 2] = g[2] - g02;
            }
            float4* op4 = reinterpret_cast<float4*>(out + (size_t)i0 * 3);
            op4[0] = make_float4(o[0], o[1], o[2],  o[3]);
            op4[1] = make_float4(o[4], o[5], o[6],  o[7]);
            op4[2] = make_float4(o[8], o[9], o[10], o[11]);
        } else {
            for (int i = i0; i < n; ++i) {
                float g[3];
                grad_sample(strain[3 * i], strain[3 * i + 1], strain[3 * i + 2], P,
                            c0pad, c1pad, g);
                out[3 * i]     = g[0] - g00;
                out[3 * i + 1] = g[1] - g01;
                out[3 * i + 2] = g[2] - g02;
            }
        }
    }
}

extern "C" void kernel_launch(void* const* d_in, const int* in_sizes, int n_in,
                              void* d_out, int out_size, void* d_ws, size_t ws_size,
                              hipStream_t stream) {
    const float* strain = (const float*)d_in[0];
    const float* c0  = (const float*)d_in[1];
    const float* sb0 = (const float*)d_in[2];
    const float* sp0 = (const float*)d_in[3];
    const float* b0  = (const float*)d_in[4];
    const float* c1  = (const float*)d_in[5];
    const float* sb1 = (const float*)d_in[6];
    const float* sp1 = (const float*)d_in[7];
    // d_in[8] = b1: no effect on gradient
    const float* ki0 = (const float*)d_in[9];
    const float* ki1 = (const float*)d_in[10];

    int n = in_sizes[0] / 3;                 // number of samples
    int ngroups = (n + 3) / 4;
    int block = 256;
    int grid = (ngroups + block - 1) / block;
    if (grid > 8192) grid = 8192;

    kan_grad<<<grid, block, 0, stream>>>(strain, (float*)d_out, n,
                                         c0, sb0, sp0, b0, c1, sb1, sp1, ki0, ki1);
}

// Round 5
// 21.026 us; speedup vs baseline: 4.8964x; 1.2506x over previous
//
#include <hip/hip_runtime.h>
#include <math.h>

#define NB 6   // GRID_N + K basis functions

struct Params {
    float sb0[3], sp0[3];
    float b0;
    float sb1, sp1;
    float ki0, ki1;
};

__device__ __forceinline__ float fexp2(float x) { return __builtin_amdgcn_exp2f(x); }
__device__ __forceinline__ float flog2(float x) { return __builtin_amdgcn_logf(x); }
__device__ __forceinline__ float frcp(float x)  { return __builtin_amdgcn_rcpf(x); }
__device__ __forceinline__ float frsq(float x)  { return __builtin_amdgcn_rsqf(x); }

// Per-cell folded cubic: for x in cell i (u = (x+3)*1.5, f = u - i):
//   S(x)  = a0 + f(a1 + f(a2 + f a3))
//   S'(x) = b0 + f(b1 + f b2)          (du/dx = 1.5 folded into b)
// where a_k are fixed combos of the 4 active control points of cell i.
// tab[t][i] = {a0,a1,a2,a3, b0,b1,b2, 0}, 16B-aligned halves.
__device__ __forceinline__ void spline_eval(float x, const float (*__restrict__ tab)[8],
                                            float& sp, float& dsp) {
    float u  = fmaf(x, 1.5f, 4.5f);
    float fi = floorf(u);
    float f  = u - fi;
    int   i  = (int)fi;
    float msk = (u >= 0.0f && u < 9.0f) ? 1.0f : 0.0f;
    i = i < 0 ? 0 : (i > 8 ? 8 : i);
    const float4 A  = *reinterpret_cast<const float4*>(&tab[i][0]);
    const float4 Bv = *reinterpret_cast<const float4*>(&tab[i][4]);
    sp  = msk * fmaf(fmaf(fmaf(A.w, f, A.z), f, A.y), f, A.x);
    dsp = msk * fmaf(fmaf(Bv.z, f, Bv.y), f, Bv.x);
}

__device__ __forceinline__ void silu_fd(float x, float& s, float& ds) {
    float e   = fexp2(-1.44269504f * x);
    float sig = frcp(1.0f + e);
    s  = x * sig;
    ds = sig * (1.0f + x * (1.0f - sig));
}

// Analytic gradient of W(s1,s2,s3), log2-space formulation (validated r4):
//   t1 = m - r, t2 = m + r; det = t1 t2
//   x0 = exp2(k(Lt1/3 - Lt2/6)), x1 symmetric, x2 = ki1*0.5*ln(det)
//   gadb[X] = (A+B)*dm[X] + (B-A)*dr[X] + C*dDet[X];  dr=0 at h2<=0 (JAX where)
__device__ void grad_sample(float s1, float s2, float s3, const Params& P,
                            const float (*__restrict__ tab)[9][8], float g[3]) {
    float a   = fmaf(2.0f, s1, 1.0f);
    float d   = fmaf(2.0f, s2, 1.0f);
    float b   = s3;
    float m   = 0.5f * (a + d);
    float amd = a - d;
    float h2  = fmaf(0.25f * amd, amd, b * b);
    bool  pos = h2 > 0.0f;
    float irr = pos ? frsq(h2) : 0.0f;    // 1/r (0 at h2<=0)
    float r   = h2 * irr;                 // sqrt(h2), exactly 0 at h2<=0
    float t1  = m - r, t2 = m + r;
    float invDet = frcp(t1 * t2);
    float invt1 = t2 * invDet, invt2 = t1 * invDet;
    float Lt1 = flog2(t1), Lt2 = flog2(t2);
    float k   = P.ki0;
    float x0  = fexp2(k * (Lt1 * (1.0f / 3.0f) - Lt2 * (1.0f / 6.0f)));
    float x1  = fexp2(k * (Lt2 * (1.0f / 3.0f) - Lt1 * (1.0f / 6.0f)));
    float x2  = P.ki1 * 0.34657359f * (Lt1 + Lt2);   // ki1 * 0.5*ln2*log2(det)

    // ---- layer 1 ----
    float xs[3] = {x0, x1, x2};
    float hacc  = P.b0;
    float gx[3];
#pragma unroll
    for (int i = 0; i < 3; ++i) {
        float sp, dsp;
        spline_eval(xs[i], tab[i], sp, dsp);
        float si, dsi; silu_fd(xs[i], si, dsi);
        hacc += P.sb0[i] * si + P.sp0[i] * sp;
        gx[i] = P.sb0[i] * dsi + P.sp0[i] * dsp;
    }
    // ---- layer 2 ----
    float sp2, dsp2;
    spline_eval(hacc, tab[3], sp2, dsp2);
    float si2, dsi2; silu_fd(hacc, si2, dsi2);
    float dWdh = P.sb1 * dsi2 + P.sp1 * dsp2;

    // ---- collapse to strain gradient ----
    float P0 = dWdh * gx[0] * x0 * k;
    float P1 = dWdh * gx[1] * x1 * k;
    float w2c = dWdh * gx[2];
    float A = 0.5f * P0 * invt1;
    float B = 0.5f * P1 * invt2;
    float C = invDet * (0.5f * P.ki1 * w2c - (P0 + P1) * (1.0f / 6.0f));
    float dr0 = 0.25f * amd * irr;
    float dr2 = b * irr;
    float ApB = A + B, BmA = B - A;
    float h05 = 0.5f * ApB;
    float gA = h05 + BmA * dr0 + C * d;
    float gD = h05 - BmA * dr0 + C * a;
    float gB = BmA * dr2 - 2.0f * b * C;
    g[0] = 2.0f * gA;
    g[1] = 2.0f * gD;
    g[2] = gB;
}

__global__ __launch_bounds__(256) void kan_grad(
        const float* __restrict__ strain, float* __restrict__ out, int n,
        const float* __restrict__ c0, const float* __restrict__ sb0,
        const float* __restrict__ sp0, const float* __restrict__ b0,
        const float* __restrict__ c1, const float* __restrict__ sb1,
        const float* __restrict__ sp1, const float* __restrict__ ki0,
        const float* __restrict__ ki1) {
    __shared__ float tab[4][9][8];
    __shared__ float g0s[3];

    const int t = threadIdx.x;
    if (t < 36) {
        int tbl = t / 9, cell = t % 9;
        const float* cp = (tbl < 3) ? (c0 + tbl * NB) : c1;
        float cv[4];
#pragma unroll
        for (int kk = 0; kk < 4; ++kk) {
            int j = cell + kk - 3;
            cv[kk] = (j >= 0 && j < NB) ? cp[j] : 0.0f;
        }
        const float c16 = 1.0f / 6.0f;
        float a0 = (cv[0] + 4.0f * cv[1] + cv[2]) * c16;
        float a1 = (cv[2] - cv[0]) * 0.5f;
        float a2 = (cv[0] - 2.0f * cv[1] + cv[2]) * 0.5f;
        float a3 = (cv[3] - cv[0] + 3.0f * (cv[1] - cv[2])) * c16;
        tab[tbl][cell][0] = a0;
        tab[tbl][cell][1] = a1;
        tab[tbl][cell][2] = a2;
        tab[tbl][cell][3] = a3;
        tab[tbl][cell][4] = 1.5f * a1;
        tab[tbl][cell][5] = 3.0f * a2;
        tab[tbl][cell][6] = 4.5f * a3;
        tab[tbl][cell][7] = 0.0f;
    }

    Params P;
#pragma unroll
    for (int i = 0; i < 3; ++i) { P.sb0[i] = sb0[i]; P.sp0[i] = sp0[i]; }
    P.b0 = b0[0];
    P.sb1 = sb1[0]; P.sp1 = sp1[0];
    P.ki0 = ki0[0]; P.ki1 = ki1[0];

    __syncthreads();
    if (t == 0) {
        float g0[3];
        grad_sample(0.0f, 0.0f, 0.0f, P, tab, g0);
        g0s[0] = g0[0]; g0s[1] = g0[1]; g0s[2] = g0[2];
    }
    __syncthreads();
    const float g00 = g0s[0], g01 = g0s[1], g02 = g0s[2];

    const int ngroups = (n + 3) >> 2;  // 4 samples (= 3 float4) per thread-task
    for (int gi = blockIdx.x * blockDim.x + threadIdx.x; gi < ngroups;
         gi += gridDim.x * blockDim.x) {
        int i0 = gi * 4;
        if (i0 + 4 <= n) {
            const float4* sp4 = reinterpret_cast<const float4*>(strain + (size_t)i0 * 3);
            float4 v0 = sp4[0], v1 = sp4[1], v2 = sp4[2];
            float in[12] = {v0.x, v0.y, v0.z, v0.w,
                            v1.x, v1.y, v1.z, v1.w,
                            v2.x, v2.y, v2.z, v2.w};
            float o[12];
#pragma unroll
            for (int kk = 0; kk < 4; ++kk) {
                float g[3];
                grad_sample(in[3 * kk], in[3 * kk + 1], in[3 * kk + 2], P, tab, g);
                o[3 * kk]     = g[0] - g00;
                o[3 * kk + 1] = g[1] - g01;
                o[3 * kk + 2] = g[2] - g02;
            }
            float4* op4 = reinterpret_cast<float4*>(out + (size_t)i0 * 3);
            op4[0] = make_float4(o[0], o[1], o[2],  o[3]);
            op4[1] = make_float4(o[4], o[5], o[6],  o[7]);
            op4[2] = make_float4(o[8], o[9], o[10], o[11]);
        } else {
            for (int i = i0; i < n; ++i) {
                float g[3];
                grad_sample(strain[3 * i], strain[3 * i + 1], strain[3 * i + 2], P,
                            tab, g);
                out[3 * i]     = g[0] - g00;
                out[3 * i + 1] = g[1] - g01;
                out[3 * i + 2] = g[2] - g02;
            }
        }
    }
}

extern "C" void kernel_launch(void* const* d_in, const int* in_sizes, int n_in,
                              void* d_out, int out_size, void* d_ws, size_t ws_size,
                              hipStream_t stream) {
    const float* strain = (const float*)d_in[0];
    const float* c0  = (const float*)d_in[1];
    const float* sb0 = (const float*)d_in[2];
    const float* sp0 = (const float*)d_in[3];
    const float* b0  = (const float*)d_in[4];
    const float* c1  = (const float*)d_in[5];
    const float* sb1 = (const float*)d_in[6];
    const float* sp1 = (const float*)d_in[7];
    // d_in[8] = b1: no effect on gradient
    const float* ki0 = (const float*)d_in[9];
    const float* ki1 = (const float*)d_in[10];

    int n = in_sizes[0] / 3;                 // number of samples
    int ngroups = (n + 3) / 4;
    int block = 256;
    int grid = (ngroups + block - 1) / block;
    if (grid > 8192) grid = 8192;

    kan_grad<<<grid, block, 0, stream>>>(strain, (float*)d_out, n,
                                         c0, sb0, sp0, b0, c1, sb1, sp1, ki0, ki1);
}